// Round 3
// baseline (163.852 us; speedup 1.0000x reference)
//
#include <hip/hip_runtime.h>

#define N 1024
#define H 256
#define EH 128

__device__ __forceinline__ float fast_silu(float x) {
    float u = __builtin_amdgcn_exp2f(x * -1.44269504088896340736f);
    return x * __builtin_amdgcn_rcpf(1.0f + u);
}

// ---------------- K1: node MLP + src/dst/ns + edge-weight prepack ----------------
// grid 256 blocks x 1024 threads; 4 nodes per block; reduction split across 4 segs
__global__ __launch_bounds__(1024) void k_node(
    const float* __restrict__ h, const float* __restrict__ dl, const float* __restrict__ temb,
    const float* __restrict__ np1_w, const float* __restrict__ np1_b,
    const float* __restrict__ np2_w, const float* __restrict__ np2_b,
    const float* __restrict__ src_w, const float* __restrict__ src_b,
    const float* __restrict__ dst_w, const float* __restrict__ dst_b,
    const float* __restrict__ ns_w, const float* __restrict__ ns_b,
    const float* __restrict__ eg1_w, const float* __restrict__ eg1_b,
    const float* __restrict__ eg2_w,
    float* __restrict__ nh, float* __restrict__ srcv, float* __restrict__ dstv,
    float* __restrict__ nsv, float* __restrict__ wp)
{
    __shared__ float feat[4][264];
    __shared__ float sred[4][4][256];   // [tile][seg][j]
    __shared__ float gred[4][3][4];
    const int tid = threadIdx.x;
    const int j   = tid & 255;
    const int seg = tid >> 8;
    const int n0  = blockIdx.x * 4;

    // block 0: prepack edge MLP weights, stride 8 per k:
    // [wx, wy, wz, wd, b, w2', 0, 0]; wx..b scaled by -log2e, w2' by -ln2
    if (blockIdx.x == 0 && tid < EH) {
        const float NL2E = -1.44269504088896340736f;
        const float NLN2 = -0.69314718055994530942f;
        float4 a;
        a.x = NL2E * eg1_w[0 * EH + tid];
        a.y = NL2E * eg1_w[1 * EH + tid];
        a.z = NL2E * eg1_w[2 * EH + tid];
        a.w = NL2E * eg1_w[3 * EH + tid];
        ((float4*)wp)[tid * 2 + 0] = a;
        float4 b;
        b.x = NL2E * eg1_b[tid];
        b.y = NLN2 * eg2_w[tid];
        b.z = 0.0f; b.w = 0.0f;
        ((float4*)wp)[tid * 2 + 1] = b;
    }

    // stage features [h | delta_local | t_emb | pad]
    for (int idx = tid; idx < 4 * 264; idx += 1024) {
        int t = idx / 264, i = idx % 264;
        int n = n0 + t;
        float v = 0.0f;
        if (i < H)            v = h[n * H + i];
        else if (i < H + 3)   v = dl[n * 3 + (i - H)];
        else if (i < H + 6)   v = temb[n * 3 + (i - H - 3)];
        feat[t][i] = v;
    }
    __syncthreads();

    // L1: 262 -> 256, seg s handles i in [66s, 66s+66) (last: 64)
    {
        float a0 = 0.f, a1 = 0.f, a2 = 0.f, a3 = 0.f;
        const int lo = seg * 66;
        const int hi = lo + ((seg == 3) ? 64 : 66);
        for (int i = lo; i < hi; i += 2) {
            float w0 = np1_w[i * H + j];
            float w1 = np1_w[(i + 1) * H + j];
            float2 f0 = *(const float2*)&feat[0][i];
            float2 f1 = *(const float2*)&feat[1][i];
            float2 f2 = *(const float2*)&feat[2][i];
            float2 f3 = *(const float2*)&feat[3][i];
            a0 = fmaf(f0.x, w0, fmaf(f0.y, w1, a0));
            a1 = fmaf(f1.x, w0, fmaf(f1.y, w1, a1));
            a2 = fmaf(f2.x, w0, fmaf(f2.y, w1, a2));
            a3 = fmaf(f3.x, w0, fmaf(f3.y, w1, a3));
        }
        sred[0][seg][j] = a0;
        sred[1][seg][j] = a1;
        sred[2][seg][j] = a2;
        sred[3][seg][j] = a3;
    }
    __syncthreads();
    {
        float s = sred[seg][0][j] + sred[seg][1][j] + sred[seg][2][j] + sred[seg][3][j] + np1_b[j];
        feat[seg][j] = fast_silu(s);
    }
    __syncthreads();

    // L2: 256 -> 256, seg s handles i in [64s, 64s+64)
    {
        float a0 = 0.f, a1 = 0.f, a2 = 0.f, a3 = 0.f;
        const int lo = seg * 64;
        for (int i = lo; i < lo + 64; i += 2) {
            float w0 = np2_w[i * H + j];
            float w1 = np2_w[(i + 1) * H + j];
            float2 f0 = *(const float2*)&feat[0][i];
            float2 f1 = *(const float2*)&feat[1][i];
            float2 f2 = *(const float2*)&feat[2][i];
            float2 f3 = *(const float2*)&feat[3][i];
            a0 = fmaf(f0.x, w0, fmaf(f0.y, w1, a0));
            a1 = fmaf(f1.x, w0, fmaf(f1.y, w1, a1));
            a2 = fmaf(f2.x, w0, fmaf(f2.y, w1, a2));
            a3 = fmaf(f3.x, w0, fmaf(f3.y, w1, a3));
        }
        sred[0][seg][j] = a0;
        sred[1][seg][j] = a1;
        sred[2][seg][j] = a2;
        sred[3][seg][j] = a3;
    }
    __syncthreads();

    float h2 = fast_silu(sred[seg][0][j] + sred[seg][1][j] + sred[seg][2][j] + sred[seg][3][j] + np2_b[j]);
    nh[(n0 + seg) * H + j] = h2;

    {
        float ps = h2 * src_w[j], pd = h2 * dst_w[j], pn = h2 * ns_w[j];
        const int lane = tid & 63, wvl = (tid >> 6) & 3;
#pragma unroll
        for (int o = 32; o > 0; o >>= 1) {
            ps += __shfl_down(ps, o);
            pd += __shfl_down(pd, o);
            pn += __shfl_down(pn, o);
        }
        if (lane == 0) { gred[seg][0][wvl] = ps; gred[seg][1][wvl] = pd; gred[seg][2][wvl] = pn; }
    }
    __syncthreads();
    if (tid < 4) {
        int t = tid;
        float s  = gred[t][0][0] + gred[t][0][1] + gred[t][0][2] + gred[t][0][3] + src_b[0];
        float d  = gred[t][1][0] + gred[t][1][1] + gred[t][1][2] + gred[t][1][3] + dst_b[0];
        float nl = gred[t][2][0] + gred[t][2][1] + gred[t][2][2] + gred[t][2][3] + ns_b[0];
        srcv[n0 + t] = s;
        dstv[n0 + t] = d;
        nsv[n0 + t]  = __builtin_amdgcn_rcpf(1.0f + __builtin_amdgcn_exp2f(nl * -1.44269504088896340736f));
    }
}

// ---------------- K2: per-row edge MLP + softmax + messages ----------------
// grid 1024 blocks (one per n) x 512 threads, 2 edges per thread.
// Weights read from GLOBAL with uniform index -> scalar/SMEM path, keeps DS pipe idle.
__global__ __launch_bounds__(512) void k_edge(
    const float* __restrict__ x, const float* __restrict__ frames,
    const float* __restrict__ srcv, const float* __restrict__ dstv,
    const float* __restrict__ nsv,
    const float* __restrict__ wp,
    const float* __restrict__ eg2_b, float* __restrict__ msg)
{
    __shared__ float rmax[8];
    __shared__ float rsum[8];
    __shared__ float rmsg[3][8];
    const int tid = threadIdx.x;
    const int n = blockIdx.x;

    float F[9];
#pragma unroll
    for (int q = 0; q < 9; q++) F[q] = frames[n * 9 + q];
    const float xn0 = x[n * 3 + 0], xn1 = x[n * 3 + 1], xn2 = x[n * 3 + 2];
    const float src_n = srcv[n];
    const float eg2b = eg2_b[0];

    float rl[2][3], dist[2], dstm[2], nsm[2];
#pragma unroll
    for (int e = 0; e < 2; e++) {
        int m = tid + e * 512;
        float rx = x[m * 3 + 0] - xn0;
        float ry = x[m * 3 + 1] - xn1;
        float rz = x[m * 3 + 2] - xn2;
        float r0 = F[0] * rx + F[3] * ry + F[6] * rz;
        float r1 = F[1] * rx + F[4] * ry + F[7] * rz;
        float r2 = F[2] * rx + F[5] * ry + F[8] * rz;
        rl[e][0] = r0; rl[e][1] = r1; rl[e][2] = r2;
        dist[e] = sqrtf(r0 * r0 + r1 * r1 + r2 * r2);
        dstm[e] = dstv[m];
        nsm[e]  = nsv[m];
    }

    float acc[2] = {0.f, 0.f};
#pragma unroll 8
    for (int k = 0; k < EH; k++) {
        const float wx = wp[k * 8 + 0];
        const float wy = wp[k * 8 + 1];
        const float wz = wp[k * 8 + 2];
        const float wd = wp[k * 8 + 3];
        const float bb = wp[k * 8 + 4];
        const float w2 = wp[k * 8 + 5];
#pragma unroll
        for (int e = 0; e < 2; e++) {
            float t2 = fmaf(rl[e][0], wx, fmaf(rl[e][1], wy, fmaf(rl[e][2], wz, fmaf(dist[e], wd, bb))));
            float r = __builtin_amdgcn_rcpf(1.0f + __builtin_amdgcn_exp2f(t2));
            acc[e] = fmaf(t2 * r, w2, acc[e]);
        }
    }

    float lg[2];
#pragma unroll
    for (int e = 0; e < 2; e++) {
        int m = tid + e * 512;
        lg[e] = (m == n) ? -10000.0f : (src_n + dstm[e] + acc[e] + eg2b);
    }

    const int lane = tid & 63, wv = tid >> 6;
    float mx = fmaxf(lg[0], lg[1]);
#pragma unroll
    for (int o = 32; o > 0; o >>= 1) mx = fmaxf(mx, __shfl_down(mx, o));
    if (lane == 0) rmax[wv] = mx;
    __syncthreads();
    mx = rmax[0];
#pragma unroll
    for (int q = 1; q < 8; q++) mx = fmaxf(mx, rmax[q]);

    float p[2]; float s = 0.f;
#pragma unroll
    for (int e = 0; e < 2; e++) {
        p[e] = __builtin_amdgcn_exp2f((lg[e] - mx) * 1.44269504088896340736f);
        s += p[e];
    }
#pragma unroll
    for (int o = 32; o > 0; o >>= 1) s += __shfl_down(s, o);
    if (lane == 0) rsum[wv] = s;
    __syncthreads();
    float S = rsum[0] + rsum[1] + rsum[2] + rsum[3] + rsum[4] + rsum[5] + rsum[6] + rsum[7];
    float inv = 1.0f / S;

    float a0 = 0.f, a1 = 0.f, a2 = 0.f;
#pragma unroll
    for (int e = 0; e < 2; e++) {
        float w = p[e] * inv * nsm[e];
        a0 = fmaf(w, rl[e][0], a0);
        a1 = fmaf(w, rl[e][1], a1);
        a2 = fmaf(w, rl[e][2], a2);
    }
#pragma unroll
    for (int o = 32; o > 0; o >>= 1) {
        a0 += __shfl_down(a0, o);
        a1 += __shfl_down(a1, o);
        a2 += __shfl_down(a2, o);
    }
    if (lane == 0) { rmsg[0][wv] = a0; rmsg[1][wv] = a1; rmsg[2][wv] = a2; }
    __syncthreads();
    if (tid < 3) {
        float v = 0.f;
#pragma unroll
        for (int q = 0; q < 8; q++) v += rmsg[tid][q];
        msg[n * 3 + tid] = v;
    }
}

// ---------------- K3: output MLP ----------------
// grid 256 blocks x 1024 threads; same seg-split structure as K1
__global__ __launch_bounds__(1024) void k_out(
    const float* __restrict__ nh, const float* __restrict__ dl, const float* __restrict__ msg,
    const float* __restrict__ out1_w, const float* __restrict__ out1_b,
    const float* __restrict__ out2_w, const float* __restrict__ out2_b,
    float* __restrict__ out)
{
    __shared__ float feat[4][264];
    __shared__ float sred[4][4][256];
    __shared__ float gred[4][3][4];
    const int tid = threadIdx.x;
    const int j   = tid & 255;
    const int seg = tid >> 8;
    const int n0  = blockIdx.x * 4;

    for (int idx = tid; idx < 4 * 264; idx += 1024) {
        int t = idx / 264, i = idx % 264;
        int n = n0 + t;
        float v = 0.0f;
        if (i < H)          v = nh[n * H + i];
        else if (i < H + 3) v = dl[n * 3 + (i - H)];
        else if (i < H + 6) v = msg[n * 3 + (i - H - 3)];
        feat[t][i] = v;
    }
    __syncthreads();

    {
        float a0 = 0.f, a1 = 0.f, a2 = 0.f, a3 = 0.f;
        const int lo = seg * 66;
        const int hi = lo + ((seg == 3) ? 64 : 66);
        for (int i = lo; i < hi; i += 2) {
            float w0 = out1_w[i * H + j];
            float w1 = out1_w[(i + 1) * H + j];
            float2 f0 = *(const float2*)&feat[0][i];
            float2 f1 = *(const float2*)&feat[1][i];
            float2 f2 = *(const float2*)&feat[2][i];
            float2 f3 = *(const float2*)&feat[3][i];
            a0 = fmaf(f0.x, w0, fmaf(f0.y, w1, a0));
            a1 = fmaf(f1.x, w0, fmaf(f1.y, w1, a1));
            a2 = fmaf(f2.x, w0, fmaf(f2.y, w1, a2));
            a3 = fmaf(f3.x, w0, fmaf(f3.y, w1, a3));
        }
        sred[0][seg][j] = a0;
        sred[1][seg][j] = a1;
        sred[2][seg][j] = a2;
        sred[3][seg][j] = a3;
    }
    __syncthreads();

    float hv = fast_silu(sred[seg][0][j] + sred[seg][1][j] + sred[seg][2][j] + sred[seg][3][j] + out1_b[j]);
    {
        float w0 = out2_w[j * 3 + 0], w1 = out2_w[j * 3 + 1], w2 = out2_w[j * 3 + 2];
        float p0 = hv * w0, p1 = hv * w1, p2 = hv * w2;
        const int lane = tid & 63, wvl = (tid >> 6) & 3;
#pragma unroll
        for (int o = 32; o > 0; o >>= 1) {
            p0 += __shfl_down(p0, o);
            p1 += __shfl_down(p1, o);
            p2 += __shfl_down(p2, o);
        }
        if (lane == 0) { gred[seg][0][wvl] = p0; gred[seg][1][wvl] = p1; gred[seg][2][wvl] = p2; }
    }
    __syncthreads();
    if (tid < 12) {
        int t = tid / 3, d = tid % 3;
        float v = gred[t][d][0] + gred[t][d][1] + gred[t][d][2] + gred[t][d][3] + out2_b[d];
        int n = n0 + t;
        out[n * 3 + d] = v + 0.25f * msg[n * 3 + d];
    }
}

extern "C" void kernel_launch(void* const* d_in, const int* in_sizes, int n_in,
                              void* d_out, int out_size, void* d_ws, size_t ws_size,
                              hipStream_t stream) {
    const float* h      = (const float*)d_in[0];
    const float* dl     = (const float*)d_in[1];
    const float* temb   = (const float*)d_in[2];
    const float* x      = (const float*)d_in[3];
    const float* fr     = (const float*)d_in[4];
    const float* np1_w  = (const float*)d_in[5];
    const float* np1_b  = (const float*)d_in[6];
    const float* np2_w  = (const float*)d_in[7];
    const float* np2_b  = (const float*)d_in[8];
    const float* src_w  = (const float*)d_in[9];
    const float* src_b  = (const float*)d_in[10];
    const float* dst_w  = (const float*)d_in[11];
    const float* dst_b  = (const float*)d_in[12];
    const float* ns_w   = (const float*)d_in[13];
    const float* ns_b   = (const float*)d_in[14];
    const float* eg1_w  = (const float*)d_in[15];
    const float* eg1_b  = (const float*)d_in[16];
    const float* eg2_w  = (const float*)d_in[17];
    const float* eg2_b  = (const float*)d_in[18];
    const float* out1_w = (const float*)d_in[19];
    const float* out1_b = (const float*)d_in[20];
    const float* out2_w = (const float*)d_in[21];
    const float* out2_b = (const float*)d_in[22];

    float* ws   = (float*)d_ws;
    float* nh   = ws;                   // 1024*256
    float* srcv = nh + 1024 * 256;      // 1024
    float* dstv = srcv + 1024;          // 1024
    float* nsv  = dstv + 1024;          // 1024
    float* msg  = nsv + 1024;           // 1024*3
    float* wp   = msg + 1024 * 3 + 1;   // 128*8, 16B-aligned offset (3073->3072? keep aligned)

    // ensure 16B alignment for wp (float4 stores): msg ends at offset 1024*259+... compute:
    // nh(262144)+srcv(1024)+dstv(1024)+nsv(1024)+msg(3072) = 268288 floats -> 16B aligned (268288*4 % 16 == 0)
    wp = msg + 1024 * 3;

    k_node<<<256, 1024, 0, stream>>>(h, dl, temb, np1_w, np1_b, np2_w, np2_b,
                                     src_w, src_b, dst_w, dst_b, ns_w, ns_b,
                                     eg1_w, eg1_b, eg2_w,
                                     nh, srcv, dstv, nsv, wp);
    k_edge<<<1024, 512, 0, stream>>>(x, fr, srcv, dstv, nsv, wp, eg2_b, msg);
    k_out<<<256, 1024, 0, stream>>>(nh, dl, msg, out1_w, out1_b, out2_w, out2_b, (float*)d_out);
}

// Round 4
// 163.266 us; speedup vs baseline: 1.0036x; 1.0036x over previous
//
#include <hip/hip_runtime.h>

#define N 1024
#define H 256
#define EH 128

__device__ __forceinline__ float fast_silu(float x) {
    float u = __builtin_amdgcn_exp2f(x * -1.44269504088896340736f);
    return x * __builtin_amdgcn_rcpf(1.0f + u);
}

// ---------------- K1: node MLP + src/dst/ns + edge-weight prepack ----------------
// grid 256 blocks x 1024 threads; 4 nodes per block; reduction split across 4 segs
__global__ __launch_bounds__(1024) void k_node(
    const float* __restrict__ h, const float* __restrict__ dl, const float* __restrict__ temb,
    const float* __restrict__ np1_w, const float* __restrict__ np1_b,
    const float* __restrict__ np2_w, const float* __restrict__ np2_b,
    const float* __restrict__ src_w, const float* __restrict__ src_b,
    const float* __restrict__ dst_w, const float* __restrict__ dst_b,
    const float* __restrict__ ns_w, const float* __restrict__ ns_b,
    const float* __restrict__ eg1_w, const float* __restrict__ eg1_b,
    const float* __restrict__ eg2_w,
    float* __restrict__ nh, float* __restrict__ srcv, float* __restrict__ dstv,
    float* __restrict__ nsv, float* __restrict__ wp)
{
    __shared__ float feat[4][264];
    __shared__ float sred[4][4][256];   // [tile][seg][j]
    __shared__ float gred[4][3][4];
    const int tid = threadIdx.x;
    const int j   = tid & 255;
    const int seg = tid >> 8;
    const int n0  = blockIdx.x * 4;

    // block 0: prepack edge MLP weights, stride 8 per k:
    // [wx, wy, wz, wd][b, iw, 0, 0]; wx..b scaled by -log2e; iw = 1/(-ln2 * eg2_w)
    if (blockIdx.x == 0 && tid < EH) {
        const float NL2E = -1.44269504088896340736f;
        const float NLN2 = -0.69314718055994530942f;
        float4 a;
        a.x = NL2E * eg1_w[0 * EH + tid];
        a.y = NL2E * eg1_w[1 * EH + tid];
        a.z = NL2E * eg1_w[2 * EH + tid];
        a.w = NL2E * eg1_w[3 * EH + tid];
        ((float4*)wp)[tid * 2 + 0] = a;
        float4 b;
        b.x = NL2E * eg1_b[tid];
        b.y = 1.0f / (NLN2 * eg2_w[tid]);   // iw
        b.z = 0.0f; b.w = 0.0f;
        ((float4*)wp)[tid * 2 + 1] = b;
    }

    // stage features [h | delta_local | t_emb | pad]
    for (int idx = tid; idx < 4 * 264; idx += 1024) {
        int t = idx / 264, i = idx % 264;
        int n = n0 + t;
        float v = 0.0f;
        if (i < H)            v = h[n * H + i];
        else if (i < H + 3)   v = dl[n * 3 + (i - H)];
        else if (i < H + 6)   v = temb[n * 3 + (i - H - 3)];
        feat[t][i] = v;
    }
    __syncthreads();

    // L1: 262 -> 256, seg s handles i in [66s, 66s+66) (last: 64)
    {
        float a0 = 0.f, a1 = 0.f, a2 = 0.f, a3 = 0.f;
        const int lo = seg * 66;
        const int hi = lo + ((seg == 3) ? 64 : 66);
        for (int i = lo; i < hi; i += 2) {
            float w0 = np1_w[i * H + j];
            float w1 = np1_w[(i + 1) * H + j];
            float2 f0 = *(const float2*)&feat[0][i];
            float2 f1 = *(const float2*)&feat[1][i];
            float2 f2 = *(const float2*)&feat[2][i];
            float2 f3 = *(const float2*)&feat[3][i];
            a0 = fmaf(f0.x, w0, fmaf(f0.y, w1, a0));
            a1 = fmaf(f1.x, w0, fmaf(f1.y, w1, a1));
            a2 = fmaf(f2.x, w0, fmaf(f2.y, w1, a2));
            a3 = fmaf(f3.x, w0, fmaf(f3.y, w1, a3));
        }
        sred[0][seg][j] = a0;
        sred[1][seg][j] = a1;
        sred[2][seg][j] = a2;
        sred[3][seg][j] = a3;
    }
    __syncthreads();
    {
        float s = sred[seg][0][j] + sred[seg][1][j] + sred[seg][2][j] + sred[seg][3][j] + np1_b[j];
        feat[seg][j] = fast_silu(s);
    }
    __syncthreads();

    // L2: 256 -> 256, seg s handles i in [64s, 64s+64)
    {
        float a0 = 0.f, a1 = 0.f, a2 = 0.f, a3 = 0.f;
        const int lo = seg * 64;
        for (int i = lo; i < lo + 64; i += 2) {
            float w0 = np2_w[i * H + j];
            float w1 = np2_w[(i + 1) * H + j];
            float2 f0 = *(const float2*)&feat[0][i];
            float2 f1 = *(const float2*)&feat[1][i];
            float2 f2 = *(const float2*)&feat[2][i];
            float2 f3 = *(const float2*)&feat[3][i];
            a0 = fmaf(f0.x, w0, fmaf(f0.y, w1, a0));
            a1 = fmaf(f1.x, w0, fmaf(f1.y, w1, a1));
            a2 = fmaf(f2.x, w0, fmaf(f2.y, w1, a2));
            a3 = fmaf(f3.x, w0, fmaf(f3.y, w1, a3));
        }
        sred[0][seg][j] = a0;
        sred[1][seg][j] = a1;
        sred[2][seg][j] = a2;
        sred[3][seg][j] = a3;
    }
    __syncthreads();

    float h2 = fast_silu(sred[seg][0][j] + sred[seg][1][j] + sred[seg][2][j] + sred[seg][3][j] + np2_b[j]);
    nh[(n0 + seg) * H + j] = h2;

    {
        float ps = h2 * src_w[j], pd = h2 * dst_w[j], pn = h2 * ns_w[j];
        const int lane = tid & 63, wvl = (tid >> 6) & 3;
#pragma unroll
        for (int o = 32; o > 0; o >>= 1) {
            ps += __shfl_down(ps, o);
            pd += __shfl_down(pd, o);
            pn += __shfl_down(pn, o);
        }
        if (lane == 0) { gred[seg][0][wvl] = ps; gred[seg][1][wvl] = pd; gred[seg][2][wvl] = pn; }
    }
    __syncthreads();
    if (tid < 4) {
        int t = tid;
        float s  = gred[t][0][0] + gred[t][0][1] + gred[t][0][2] + gred[t][0][3] + src_b[0];
        float d  = gred[t][1][0] + gred[t][1][1] + gred[t][1][2] + gred[t][1][3] + dst_b[0];
        float nl = gred[t][2][0] + gred[t][2][1] + gred[t][2][2] + gred[t][2][3] + ns_b[0];
        srcv[n0 + t] = s;
        dstv[n0 + t] = d;
        nsv[n0 + t]  = __builtin_amdgcn_rcpf(1.0f + __builtin_amdgcn_exp2f(nl * -1.44269504088896340736f));
    }
}

// ---------------- K2: per-row edge MLP + softmax + messages ----------------
// grid 1024 blocks (one per n) x 512 threads, 2 edges per thread.
// Weights via uniform s_load, manually double-buffered in 4-k chunks so the
// lgkmcnt(0) SMEM drain lands ~224 compute-cycles after issue (stall hidden).
__global__ __launch_bounds__(512) void k_edge(
    const float* __restrict__ x, const float* __restrict__ frames,
    const float* __restrict__ srcv, const float* __restrict__ dstv,
    const float* __restrict__ nsv,
    const float* __restrict__ wp,
    const float* __restrict__ eg2_b, float* __restrict__ msg)
{
    __shared__ float rmax[8];
    __shared__ float rsum[8];
    __shared__ float rmsg[3][8];
    const int tid = threadIdx.x;
    const int n = blockIdx.x;

    float F[9];
#pragma unroll
    for (int q = 0; q < 9; q++) F[q] = frames[n * 9 + q];
    const float xn0 = x[n * 3 + 0], xn1 = x[n * 3 + 1], xn2 = x[n * 3 + 2];
    const float src_n = srcv[n];
    const float eg2b = eg2_b[0];

    const int m0 = tid;
    const int m1 = tid + 512;
    float rl00, rl01, rl02, d0, rl10, rl11, rl12, d1, dstm0, dstm1, nsm0, nsm1;
    {
        float rx = x[m0 * 3 + 0] - xn0;
        float ry = x[m0 * 3 + 1] - xn1;
        float rz = x[m0 * 3 + 2] - xn2;
        rl00 = F[0] * rx + F[3] * ry + F[6] * rz;
        rl01 = F[1] * rx + F[4] * ry + F[7] * rz;
        rl02 = F[2] * rx + F[5] * ry + F[8] * rz;
        d0 = sqrtf(rl00 * rl00 + rl01 * rl01 + rl02 * rl02);
        dstm0 = dstv[m0];
        nsm0  = nsv[m0];
    }
    {
        float rx = x[m1 * 3 + 0] - xn0;
        float ry = x[m1 * 3 + 1] - xn1;
        float rz = x[m1 * 3 + 2] - xn2;
        rl10 = F[0] * rx + F[3] * ry + F[6] * rz;
        rl11 = F[1] * rx + F[4] * ry + F[7] * rz;
        rl12 = F[2] * rx + F[5] * ry + F[8] * rz;
        d1 = sqrtf(rl10 * rl10 + rl11 * rl11 + rl12 * rl12);
        dstm1 = dstv[m1];
        nsm1  = nsv[m1];
    }

    float acc0 = 0.f, acc1 = 0.f;
    const float4* __restrict__ Wq = (const float4*)wp;

// one k-step: Xa = {wx,wy,wz,wd}, Xb = {b, iw, -, -}
#define KSTEP(Xa, Xb)                                                                    \
    {                                                                                    \
        float t20 = fmaf(rl00, Xa.x, fmaf(rl01, Xa.y, fmaf(rl02, Xa.z, fmaf(d0, Xa.w, Xb.x)))); \
        float t21 = fmaf(rl10, Xa.x, fmaf(rl11, Xa.y, fmaf(rl12, Xa.z, fmaf(d1, Xa.w, Xb.x)))); \
        float u0 = __builtin_amdgcn_exp2f(t20);                                          \
        float u1 = __builtin_amdgcn_exp2f(t21);                                          \
        float v0 = fmaf(u0, Xb.y, Xb.y);                                                 \
        float v1 = fmaf(u1, Xb.y, Xb.y);                                                 \
        float r0 = __builtin_amdgcn_rcpf(v0);                                            \
        float r1 = __builtin_amdgcn_rcpf(v1);                                            \
        acc0 = fmaf(t20, r0, acc0);                                                      \
        acc1 = fmaf(t21, r1, acc1);                                                      \
    }

    // prologue: chunk 0 (k=0..3) into A
    float4 A0 = Wq[0], A1 = Wq[1], A2 = Wq[2], A3 = Wq[3],
           A4 = Wq[4], A5 = Wq[5], A6 = Wq[6], A7 = Wq[7];
    float4 B0, B1, B2, B3, B4, B5, B6, B7;

    for (int c = 0; c < 32; c += 2) {
        // issue chunk c+1 loads into B (always valid: c+1 <= 31)
        {
            const int i1 = (c + 1) * 8;
            B0 = Wq[i1 + 0]; B1 = Wq[i1 + 1]; B2 = Wq[i1 + 2]; B3 = Wq[i1 + 3];
            B4 = Wq[i1 + 4]; B5 = Wq[i1 + 5]; B6 = Wq[i1 + 6]; B7 = Wq[i1 + 7];
        }
        // compute chunk c from A
        KSTEP(A0, A1) KSTEP(A2, A3) KSTEP(A4, A5) KSTEP(A6, A7)
        // issue chunk c+2 loads into A (clamped; last ones unused)
        {
            const int i2 = ((c + 2 < 32) ? (c + 2) : 31) * 8;
            A0 = Wq[i2 + 0]; A1 = Wq[i2 + 1]; A2 = Wq[i2 + 2]; A3 = Wq[i2 + 3];
            A4 = Wq[i2 + 4]; A5 = Wq[i2 + 5]; A6 = Wq[i2 + 6]; A7 = Wq[i2 + 7];
        }
        // compute chunk c+1 from B
        KSTEP(B0, B1) KSTEP(B2, B3) KSTEP(B4, B5) KSTEP(B6, B7)
    }
#undef KSTEP

    const float base_n = src_n + eg2b;
    float lg0 = (m0 == n) ? -10000.0f : (base_n + dstm0 + acc0);
    float lg1 = (m1 == n) ? -10000.0f : (base_n + dstm1 + acc1);

    const int lane = tid & 63, wv = tid >> 6;
    float mx = fmaxf(lg0, lg1);
#pragma unroll
    for (int o = 32; o > 0; o >>= 1) mx = fmaxf(mx, __shfl_down(mx, o));
    if (lane == 0) rmax[wv] = mx;
    __syncthreads();
    mx = rmax[0];
#pragma unroll
    for (int q = 1; q < 8; q++) mx = fmaxf(mx, rmax[q]);

    float p0 = __builtin_amdgcn_exp2f((lg0 - mx) * 1.44269504088896340736f);
    float p1 = __builtin_amdgcn_exp2f((lg1 - mx) * 1.44269504088896340736f);
    float s = p0 + p1;
#pragma unroll
    for (int o = 32; o > 0; o >>= 1) s += __shfl_down(s, o);
    if (lane == 0) rsum[wv] = s;
    __syncthreads();
    float S = rsum[0] + rsum[1] + rsum[2] + rsum[3] + rsum[4] + rsum[5] + rsum[6] + rsum[7];
    float inv = 1.0f / S;

    float w0 = p0 * inv * nsm0;
    float w1 = p1 * inv * nsm1;
    float a0 = fmaf(w0, rl00, w1 * rl10);
    float a1 = fmaf(w0, rl01, w1 * rl11);
    float a2 = fmaf(w0, rl02, w1 * rl12);
#pragma unroll
    for (int o = 32; o > 0; o >>= 1) {
        a0 += __shfl_down(a0, o);
        a1 += __shfl_down(a1, o);
        a2 += __shfl_down(a2, o);
    }
    if (lane == 0) { rmsg[0][wv] = a0; rmsg[1][wv] = a1; rmsg[2][wv] = a2; }
    __syncthreads();
    if (tid < 3) {
        float v = 0.f;
#pragma unroll
        for (int q = 0; q < 8; q++) v += rmsg[tid][q];
        msg[n * 3 + tid] = v;
    }
}

// ---------------- K3: output MLP ----------------
// grid 256 blocks x 1024 threads; same seg-split structure as K1
__global__ __launch_bounds__(1024) void k_out(
    const float* __restrict__ nh, const float* __restrict__ dl, const float* __restrict__ msg,
    const float* __restrict__ out1_w, const float* __restrict__ out1_b,
    const float* __restrict__ out2_w, const float* __restrict__ out2_b,
    float* __restrict__ out)
{
    __shared__ float feat[4][264];
    __shared__ float sred[4][4][256];
    __shared__ float gred[4][3][4];
    const int tid = threadIdx.x;
    const int j   = tid & 255;
    const int seg = tid >> 8;
    const int n0  = blockIdx.x * 4;

    for (int idx = tid; idx < 4 * 264; idx += 1024) {
        int t = idx / 264, i = idx % 264;
        int n = n0 + t;
        float v = 0.0f;
        if (i < H)          v = nh[n * H + i];
        else if (i < H + 3) v = dl[n * 3 + (i - H)];
        else if (i < H + 6) v = msg[n * 3 + (i - H - 3)];
        feat[t][i] = v;
    }
    __syncthreads();

    {
        float a0 = 0.f, a1 = 0.f, a2 = 0.f, a3 = 0.f;
        const int lo = seg * 66;
        const int hi = lo + ((seg == 3) ? 64 : 66);
        for (int i = lo; i < hi; i += 2) {
            float w0 = out1_w[i * H + j];
            float w1 = out1_w[(i + 1) * H + j];
            float2 f0 = *(const float2*)&feat[0][i];
            float2 f1 = *(const float2*)&feat[1][i];
            float2 f2 = *(const float2*)&feat[2][i];
            float2 f3 = *(const float2*)&feat[3][i];
            a0 = fmaf(f0.x, w0, fmaf(f0.y, w1, a0));
            a1 = fmaf(f1.x, w0, fmaf(f1.y, w1, a1));
            a2 = fmaf(f2.x, w0, fmaf(f2.y, w1, a2));
            a3 = fmaf(f3.x, w0, fmaf(f3.y, w1, a3));
        }
        sred[0][seg][j] = a0;
        sred[1][seg][j] = a1;
        sred[2][seg][j] = a2;
        sred[3][seg][j] = a3;
    }
    __syncthreads();

    float hv = fast_silu(sred[seg][0][j] + sred[seg][1][j] + sred[seg][2][j] + sred[seg][3][j] + out1_b[j]);
    {
        float w0 = out2_w[j * 3 + 0], w1 = out2_w[j * 3 + 1], w2 = out2_w[j * 3 + 2];
        float p0 = hv * w0, p1 = hv * w1, p2 = hv * w2;
        const int lane = tid & 63, wvl = (tid >> 6) & 3;
#pragma unroll
        for (int o = 32; o > 0; o >>= 1) {
            p0 += __shfl_down(p0, o);
            p1 += __shfl_down(p1, o);
            p2 += __shfl_down(p2, o);
        }
        if (lane == 0) { gred[seg][0][wvl] = p0; gred[seg][1][wvl] = p1; gred[seg][2][wvl] = p2; }
    }
    __syncthreads();
    if (tid < 12) {
        int t = tid / 3, d = tid % 3;
        float v = gred[t][d][0] + gred[t][d][1] + gred[t][d][2] + gred[t][d][3] + out2_b[d];
        int n = n0 + t;
        out[n * 3 + d] = v + 0.25f * msg[n * 3 + d];
    }
}

extern "C" void kernel_launch(void* const* d_in, const int* in_sizes, int n_in,
                              void* d_out, int out_size, void* d_ws, size_t ws_size,
                              hipStream_t stream) {
    const float* h      = (const float*)d_in[0];
    const float* dl     = (const float*)d_in[1];
    const float* temb   = (const float*)d_in[2];
    const float* x      = (const float*)d_in[3];
    const float* fr     = (const float*)d_in[4];
    const float* np1_w  = (const float*)d_in[5];
    const float* np1_b  = (const float*)d_in[6];
    const float* np2_w  = (const float*)d_in[7];
    const float* np2_b  = (const float*)d_in[8];
    const float* src_w  = (const float*)d_in[9];
    const float* src_b  = (const float*)d_in[10];
    const float* dst_w  = (const float*)d_in[11];
    const float* dst_b  = (const float*)d_in[12];
    const float* ns_w   = (const float*)d_in[13];
    const float* ns_b   = (const float*)d_in[14];
    const float* eg1_w  = (const float*)d_in[15];
    const float* eg1_b  = (const float*)d_in[16];
    const float* eg2_w  = (const float*)d_in[17];
    const float* eg2_b  = (const float*)d_in[18];
    const float* out1_w = (const float*)d_in[19];
    const float* out1_b = (const float*)d_in[20];
    const float* out2_w = (const float*)d_in[21];
    const float* out2_b = (const float*)d_in[22];

    float* ws   = (float*)d_ws;
    float* nh   = ws;                   // 1024*256
    float* srcv = nh + 1024 * 256;      // 1024
    float* dstv = srcv + 1024;          // 1024
    float* nsv  = dstv + 1024;          // 1024
    float* msg  = nsv + 1024;           // 1024*3
    float* wp   = msg + 1024 * 3;       // 128*8 floats, 16B-aligned (268288*4 % 16 == 0)

    k_node<<<256, 1024, 0, stream>>>(h, dl, temb, np1_w, np1_b, np2_w, np2_b,
                                     src_w, src_b, dst_w, dst_b, ns_w, ns_b,
                                     eg1_w, eg1_b, eg2_w,
                                     nh, srcv, dstv, nsv, wp);
    k_edge<<<1024, 512, 0, stream>>>(x, fr, srcv, dstv, nsv, wp, eg2_b, msg);
    k_out<<<256, 1024, 0, stream>>>(nh, dl, msg, out1_w, out1_b, out2_w, out2_b, (float*)d_out);
}